// Round 5
// baseline (73.103 us; speedup 1.0000x reference)
//
#include <hip/hip_runtime.h>
#include <math.h>

#define GROUP 8
#define NG 4
#define C2 32
#define CTOT 64
#define L 4096
#define BB 4
#define NSAMP 2048
#define TILE 512     // samples staged per pass (16 KB)
#define THREADS 256  // 4 waves/block -> 4 (b,pos) per block
#define QPB 4

__device__ __forceinline__ float readlane_f(float v, int l) {
    return __builtin_bit_cast(float,
        __builtin_amdgcn_readlane(__builtin_bit_cast(int, v), l));
}

// One wave per (b,pos): all 64 coefficients are wave-uniform -> SGPRs via
// readlane; inner FMA = v_fma(sgpr, vgpr, vgpr). Lane l scans samples
// n = t*TILE + i*64 + l (32 samples/lane). Split form sum(ca*s^2)+sum(cb*s)
// keeps <=1 SGPR operand per instruction.
// ca = 0.5*(1-iv), cb = mu*iv (rc dropped, -nlp folded: argmax-invariant).
// 8 blocks/CU (16KB LDS, 256 thr, VGPR<=64) -> 8 waves/SIMD.
__global__ __launch_bounds__(THREADS, 8) void gqreg_kernel(
    const float* __restrict__ z, const float* __restrict__ prior,
    float* __restrict__ out /* zhat [B][C2][L] then indices-as-float [B][NG][L] */)
{
    __shared__ float4 s_lo[TILE];   // 8 KB: sample n, g=0..3
    __shared__ float4 s_hi[TILE];   // 8 KB: sample n, g=4..7

    const int tid = threadIdx.x;
    const int lane = tid & 63;
    const int w = tid >> 6;
    const int Q = blockIdx.x * QPB + w;     // (b,pos) of this wave
    const int b = Q >> 12;
    const int pos = Q & (L - 1);
    const float4* p4 = (const float4*)prior;

    // ---- stage tile 0 (each thread stages 2 samples) ----
    {
        int n0 = tid, n1 = tid + THREADS;
        s_lo[n0] = p4[2 * n0];     s_hi[n0] = p4[2 * n0 + 1];
        s_lo[n1] = p4[2 * n1];     s_hi[n1] = p4[2 * n1 + 1];
    }

    // ---- coefficients: lane c (=lane&31) computes channel c, then readlane
    //      to wave-uniform (SGPR) values ----
    const int c = lane & 31;
    const float* zb = z + (size_t)b * CTOT * L + pos;
    float mu = zb[(size_t)c * L];
    float lv = zb[(size_t)(C2 + c) * L];
    lv = fminf(fmaxf(lv, -30.f), 20.f);
    float iv = expf(-lv);
    float cav = 0.5f - 0.5f * iv;
    float cbv = mu * iv;

    float ca_u[NG][GROUP], cb_u[NG][GROUP];   // wave-uniform -> SGPRs
    #pragma unroll
    for (int ns = 0; ns < NG; ++ns) {
        #pragma unroll
        for (int g = 0; g < GROUP; ++g) {
            int ch = g * NG + ns;
            ca_u[ns][g] = readlane_f(cav, ch);
            cb_u[ns][g] = readlane_f(cbv, ch);
        }
    }

    float best[NG] = {-INFINITY, -INFINITY, -INFINITY, -INFINITY};
    int bidx[NG] = {0, 0, 0, 0};

    #pragma unroll
    for (int t = 0; t < NSAMP / TILE; ++t) {
        if (t > 0) {
            __syncthreads();   // previous tile fully scanned
            int base = t * TILE;
            int n0 = tid, n1 = tid + THREADS;
            s_lo[n0] = p4[2 * (base + n0)];  s_hi[n0] = p4[2 * (base + n0) + 1];
            s_lo[n1] = p4[2 * (base + n1)];  s_hi[n1] = p4[2 * (base + n1) + 1];
        }
        __syncthreads();

        #pragma unroll 4
        for (int i = 0; i < TILE / 64; ++i) {
            int nl = i * 64 + lane;
            int n = t * TILE + nl;
            float4 u = s_lo[nl], v = s_hi[nl];
            float s0 = u.x, s1 = u.y, s2 = u.z, s3 = u.w;
            float s4 = v.x, s5 = v.y, s6 = v.z, s7 = v.w;
            float q0 = s0 * s0, q1 = s1 * s1, q2 = s2 * s2, q3 = s3 * s3;
            float q4 = s4 * s4, q5 = s5 * s5, q6 = s6 * s6, q7 = s7 * s7;
            #pragma unroll
            for (int ns = 0; ns < NG; ++ns) {
                float a1 = ca_u[ns][0] * q0;
                a1 = fmaf(ca_u[ns][1], q1, a1);
                a1 = fmaf(ca_u[ns][2], q2, a1);
                a1 = fmaf(ca_u[ns][3], q3, a1);
                a1 = fmaf(ca_u[ns][4], q4, a1);
                a1 = fmaf(ca_u[ns][5], q5, a1);
                a1 = fmaf(ca_u[ns][6], q6, a1);
                a1 = fmaf(ca_u[ns][7], q7, a1);
                float a2 = cb_u[ns][0] * s0;
                a2 = fmaf(cb_u[ns][1], s1, a2);
                a2 = fmaf(cb_u[ns][2], s2, a2);
                a2 = fmaf(cb_u[ns][3], s3, a2);
                a2 = fmaf(cb_u[ns][4], s4, a2);
                a2 = fmaf(cb_u[ns][5], s5, a2);
                a2 = fmaf(cb_u[ns][6], s6, a2);
                a2 = fmaf(cb_u[ns][7], s7, a2);
                float sc = a1 + a2;
                if (sc > best[ns]) { best[ns] = sc; bidx[ns] = n; }
            }
        }
    }

    // ---- reduce argmax across all 64 lanes (tie -> lowest n) ----
    #pragma unroll
    for (int ns = 0; ns < NG; ++ns) {
        #pragma unroll
        for (int m = 1; m < 64; m <<= 1) {
            float os = __shfl_xor(best[ns], m, 64);
            int oi = __shfl_xor(bidx[ns], m, 64);
            if (os > best[ns] || (os == best[ns] && oi < bidx[ns])) {
                best[ns] = os; bidx[ns] = oi;
            }
        }
    }

    // ---- lane 0 writes outputs; zhat gathered from global prior (L2-hot) ----
    if (lane == 0) {
        float* zout = out + (size_t)b * C2 * L + pos;
        float* iout = out + (size_t)BB * C2 * L + (size_t)b * NG * L + pos;
        #pragma unroll
        for (int ns = 0; ns < NG; ++ns) {
            int n = bidx[ns];
            iout[(size_t)ns * L] = (float)n;
            float4 u = p4[2 * n], v = p4[2 * n + 1];
            float sv[GROUP] = {u.x, u.y, u.z, u.w, v.x, v.y, v.z, v.w};
            #pragma unroll
            for (int g = 0; g < GROUP; ++g) {
                zout[(size_t)(g * NG + ns) * L] = sv[g];
            }
        }
    }
}

extern "C" void kernel_launch(void* const* d_in, const int* in_sizes, int n_in,
                              void* d_out, int out_size, void* d_ws, size_t ws_size,
                              hipStream_t stream) {
    const float* z = (const float*)d_in[0];
    const float* prior = (const float*)d_in[1];
    float* out = (float*)d_out;
    dim3 grid((BB * L) / QPB);
    dim3 block(THREADS);
    hipLaunchKernelGGL(gqreg_kernel, grid, block, 0, stream, z, prior, out);
}

// Round 6
// 66.794 us; speedup vs baseline: 1.0945x; 1.0945x over previous
//
#include <hip/hip_runtime.h>
#include <math.h>

#define GROUP 8
#define NG 4
#define C2 32
#define CTOT 64
#define L 4096
#define BB 4
#define NSAMP 2048
#define TILE 1024   // samples staged per pass (32 KB)
#define KL 16       // n-stripes per q
#define QPB 32      // (b,pos) pairs per block
#define THREADS 512

typedef float v2f __attribute__((ext_vector_type(2)));

__device__ __forceinline__ v2f pk_fma(v2f a, v2f b, v2f c) {
    v2f d;
    asm("v_pk_fma_f32 %0, %1, %2, %3" : "=v"(d) : "v"(a), "v"(b), "v"(c));
    return d;
}

// R2 structure + packed fp32 FMA. Block: 512 threads; tid>>4 = q -> (b,pos),
// tid&15 = k -> n-stripe (n = nn*16+k). Each thread owns its (b,pos)'s 4
// ns-rows (best LDS amortization). Samples staged in 2x 1024-sample tiles
// (32 KB LDS). NO min-waves launch bound (R3 lesson: forcing 8/EU -> 32-VGPR
// target -> scratch spills); natural VGPR ~90.
//
// score'[r,n] = sum_g (ca*s + cb)*s, ca = 0.5*(1-iv), cb = mu*iv
// (row-constant rc dropped, -nlp folded into ca: both argmax-invariant).
__global__ __launch_bounds__(THREADS) void gqreg_kernel(
    const float* __restrict__ z, const float* __restrict__ prior,
    float* __restrict__ out /* zhat [B][C2][L] then indices-as-float [B][NG][L] */)
{
    __shared__ float4 s_lo[TILE];   // 16 KB: sample n, g=0..3
    __shared__ float4 s_hi[TILE];   // 16 KB: sample n, g=4..7

    const int tid = threadIdx.x;
    const float4* p4 = (const float4*)prior;

    // ---- stage tile 0 (overlaps coeff computation) ----
    #pragma unroll
    for (int i = 0; i < 2; ++i) {
        int n = tid + i * THREADS;
        s_lo[n] = p4[2 * n];
        s_hi[n] = p4[2 * n + 1];
    }

    // ---- per-row coefficients, packed in v2f over g-pairs ----
    const int k = tid & (KL - 1);
    const int q = tid >> 4;
    const int Q = blockIdx.x * QPB + q;     // 0 .. B*L-1
    const int b = Q >> 12;
    const int pos = Q & (L - 1);
    const float* zb = z + (size_t)b * CTOT * L + pos;

    v2f ca2[NG][4];   // 0.5*(1 - inv_var)
    v2f cb2[NG][4];   // mu * inv_var
    #pragma unroll
    for (int ns = 0; ns < NG; ++ns) {
        #pragma unroll
        for (int gp = 0; gp < 4; ++gp) {
            #pragma unroll
            for (int e = 0; e < 2; ++e) {
                int g = gp * 2 + e;
                int ch = g * NG + ns;
                float mu = zb[(size_t)ch * L];
                float lv = zb[(size_t)(C2 + ch) * L];
                lv = fminf(fmaxf(lv, -30.f), 20.f);
                float iv = expf(-lv);
                ca2[ns][gp][e] = 0.5f - 0.5f * iv;
                cb2[ns][gp][e] = mu * iv;
            }
        }
    }

    float best[NG] = {-INFINITY, -INFINITY, -INFINITY, -INFINITY};
    int bidx[NG] = {0, 0, 0, 0};

    #pragma unroll
    for (int t = 0; t < NSAMP / TILE; ++t) {
        if (t > 0) {
            __syncthreads();   // previous tile fully scanned
            #pragma unroll
            for (int i = 0; i < 2; ++i) {
                int nl = tid + i * THREADS;
                int n = t * TILE + nl;
                s_lo[nl] = p4[2 * n];
                s_hi[nl] = p4[2 * n + 1];
            }
        }
        __syncthreads();

        #pragma unroll 4
        for (int nn = 0; nn < TILE / KL; ++nn) {
            int nl = nn * KL + k;
            int n = t * TILE + nl;
            float4 u = s_lo[nl], v = s_hi[nl];
            v2f sp0 = {u.x, u.y}, sp1 = {u.z, u.w};
            v2f sp2 = {v.x, v.y}, sp3 = {v.z, v.w};
            #pragma unroll
            for (int ns = 0; ns < NG; ++ns) {
                v2f acc = {0.f, 0.f};
                v2f tt;
                tt = pk_fma(ca2[ns][0], sp0, cb2[ns][0]); acc = pk_fma(tt, sp0, acc);
                tt = pk_fma(ca2[ns][1], sp1, cb2[ns][1]); acc = pk_fma(tt, sp1, acc);
                tt = pk_fma(ca2[ns][2], sp2, cb2[ns][2]); acc = pk_fma(tt, sp2, acc);
                tt = pk_fma(ca2[ns][3], sp3, cb2[ns][3]); acc = pk_fma(tt, sp3, acc);
                float sc = acc.x + acc.y;
                if (sc > best[ns]) { best[ns] = sc; bidx[ns] = n; }
            }
        }
    }

    // ---- reduce argmax across the 16 stripe lanes (tie -> lowest n) ----
    #pragma unroll
    for (int ns = 0; ns < NG; ++ns) {
        #pragma unroll
        for (int m = 1; m < KL; m <<= 1) {
            float os = __shfl_xor(best[ns], m, 64);
            int oi = __shfl_xor(bidx[ns], m, 64);
            if (os > best[ns] || (os == best[ns] && oi < bidx[ns])) {
                best[ns] = os; bidx[ns] = oi;
            }
        }
    }

    // ---- write outputs (lane k==0); zhat gathered from global prior (L2-hot) ----
    if (k == 0) {
        float* zout = out + (size_t)b * C2 * L + pos;
        float* iout = out + (size_t)BB * C2 * L + (size_t)b * NG * L + pos;
        #pragma unroll
        for (int ns = 0; ns < NG; ++ns) {
            int n = bidx[ns];
            iout[(size_t)ns * L] = (float)n;
            float4 u = p4[2 * n], v = p4[2 * n + 1];
            float sv[GROUP] = {u.x, u.y, u.z, u.w, v.x, v.y, v.z, v.w};
            #pragma unroll
            for (int g = 0; g < GROUP; ++g) {
                zout[(size_t)(g * NG + ns) * L] = sv[g];
            }
        }
    }
}

extern "C" void kernel_launch(void* const* d_in, const int* in_sizes, int n_in,
                              void* d_out, int out_size, void* d_ws, size_t ws_size,
                              hipStream_t stream) {
    const float* z = (const float*)d_in[0];
    const float* prior = (const float*)d_in[1];
    float* out = (float*)d_out;
    dim3 grid((BB * L) / QPB);
    dim3 block(THREADS);
    hipLaunchKernelGGL(gqreg_kernel, grid, block, 0, stream, z, prior, out);
}

// Round 7
// 37.186 us; speedup vs baseline: 1.9659x; 1.7962x over previous
//
#include <hip/hip_runtime.h>
#include <math.h>

#define L 4096
#define C2 32
#define CTOT 64
#define BB 4
#define NG 4
#define NSAMP 2048
#define SETSZ 512              // samples staged per set (48 KB LDS)
#define NSETS (NSAMP / SETSZ)
#define NTILE (SETSZ / 16)     // 32 16-sample tiles per set
#define TPB 512                // 8 waves; each wave owns 16 rows
#define ROWSPB 128             // 8 * 16

typedef _Float16 half8 __attribute__((ext_vector_type(8)));
typedef float f32x4 __attribute__((ext_vector_type(4)));

__device__ __forceinline__ void split3(float x, _Float16& h, _Float16& m, _Float16& l) {
    h = (_Float16)x;
    float r1 = x - (float)h;
    m = (_Float16)r1;
    float r2 = r1 - (float)m;
    l = (_Float16)r2;
}

// score[r,n] = sum_g ca*s^2 + cb*s, ca = 0.5*(1-iv) (nlp folded), cb = mu*iv
// (rc dropped; both argmax-invariant — established R2..R6, absmax 0).
// fp32 emulated on f16 MFMA via 3-way split (h/m/l = 33 mantissa bits):
//   [Ah|Am]*[Bh|Bm] -> hh+mm ; [Ah|Am]*[Bm|Bh] -> hm+mh ; [Ah|Al]*[Bl|Bh] -> hl+lh
// dropped terms ~2^-33 — far below fp32 reorder noise already passing.
// LDS per 16-sample tile: 6 rows x 16 samples x 8 f16:
//   row0 s2h, row1 sh, row2 s2m, row3 sm, row4 s2l, row5 sl
__global__ __launch_bounds__(TPB) void gqreg_kernel(
    const float* __restrict__ z, const float* __restrict__ prior,
    float* __restrict__ out /* zhat [B][C2][L] then indices-as-float [B][NG][L] */)
{
    __shared__ _Float16 smem[NTILE * 6 * 16 * 8];   // 48 KB
    char* sbase = (char*)smem;

    const int tid = threadIdx.x;
    const int lane = tid & 63;
    const int w = tid >> 6;          // wave id 0..7
    const int i = lane & 15;         // A-row / B-col index
    const int kb = lane >> 4;        // k-block 0..3

    // ---- A-side coefficients: lane (i,kb) holds 8 f16 k-elems of row i ----
    const int r0 = blockIdx.x * ROWSPB + w * 16 + i;
    const int b0 = r0 >> 14, pos0 = (r0 >> 2) & (L - 1), ns0 = r0 & 3;
    const float* zb = z + (size_t)b0 * CTOT * L + pos0;

    half8 a_hm, a_hl;
    #pragma unroll
    for (int g = 0; g < 8; ++g) {
        float lv = zb[(size_t)(C2 + g * NG + ns0) * L];
        lv = fminf(fmaxf(lv, -30.f), 20.f);
        float iv = expf(-lv);
        float x;
        if (kb & 1) {
            float mu = zb[(size_t)(g * NG + ns0) * L];
            x = mu * iv;
        } else {
            x = 0.5f - 0.5f * iv;
        }
        _Float16 xh, xm, xl;
        split3(x, xh, xm, xl);
        a_hm[g] = (kb < 2) ? xh : xm;
        a_hl[g] = (kb < 2) ? xh : xl;
    }

    // ---- per-lane LDS byte offsets for the three B fragments ----
    const int nl16 = i * 16;
    const int off1 = kb * 256 + nl16;                                 // [Bh|Bm]
    const int off2 = (kb ^ 2) * 256 + nl16;                           // [Bm|Bh]
    const int off3 = ((kb < 2) ? (kb + 4) : (kb - 2)) * 256 + nl16;   // [Bl|Bh]

    float best[4] = {-INFINITY, -INFINITY, -INFINITY, -INFINITY};
    int bidx[4] = {0, 0, 0, 0};
    const f32x4 zero4 = {0.f, 0.f, 0.f, 0.f};

    for (int set = 0; set < NSETS; ++set) {
        if (set > 0) __syncthreads();   // previous set fully scanned

        // ---- stage set: thread tid splits sample (set*512 + tid) ----
        {
            int st = tid >> 4, snl = tid & 15;
            const float4* ps = (const float4*)(prior + (size_t)(set * SETSZ + tid) * 8);
            float4 u = ps[0], v = ps[1];
            float s[8] = {u.x, u.y, u.z, u.w, v.x, v.y, v.z, v.w};
            half8 qh, qm, ql, vh, vm, vl;
            #pragma unroll
            for (int g = 0; g < 8; ++g) {
                _Float16 h, m, l;
                split3(s[g] * s[g], h, m, l);
                qh[g] = h; qm[g] = m; ql[g] = l;
                split3(s[g], h, m, l);
                vh[g] = h; vm[g] = m; vl[g] = l;
            }
            char* tb = sbase + st * 1536 + snl * 16;
            *(half8*)(tb + 0 * 256) = qh;
            *(half8*)(tb + 1 * 256) = vh;
            *(half8*)(tb + 2 * 256) = qm;
            *(half8*)(tb + 3 * 256) = vm;
            *(half8*)(tb + 4 * 256) = ql;
            *(half8*)(tb + 5 * 256) = vl;
        }
        __syncthreads();

        int ncand = set * SETSZ + i;
        #pragma unroll
        for (int t = 0; t < NTILE; ++t) {
            const int tb = t * 1536;
            half8 f1 = *(const half8*)(sbase + tb + off1);
            half8 f2 = *(const half8*)(sbase + tb + off2);
            half8 f3 = *(const half8*)(sbase + tb + off3);
            f32x4 acc = __builtin_amdgcn_mfma_f32_16x16x32_f16(a_hm, f1, zero4, 0, 0, 0);
            acc = __builtin_amdgcn_mfma_f32_16x16x32_f16(a_hm, f2, acc, 0, 0, 0);
            acc = __builtin_amdgcn_mfma_f32_16x16x32_f16(a_hl, f3, acc, 0, 0, 0);
            #pragma unroll
            for (int j = 0; j < 4; ++j) {
                if (acc[j] > best[j]) { best[j] = acc[j]; bidx[j] = ncand; }
            }
            ncand += 16;
        }
    }

    // ---- reduce argmax across the 16 col-lanes of each kb group ----
    #pragma unroll
    for (int j = 0; j < 4; ++j) {
        #pragma unroll
        for (int m = 1; m < 16; m <<= 1) {
            float os = __shfl_xor(best[j], m, 64);
            int oi = __shfl_xor(bidx[j], m, 64);
            if (os > best[j] || (os == best[j] && oi < bidx[j])) {
                best[j] = os; bidx[j] = oi;
            }
        }
    }

    // ---- lane i==0 of each kb group writes its 4 D-rows (kb*4+j) ----
    if (i == 0) {
        #pragma unroll
        for (int j = 0; j < 4; ++j) {
            int rr = blockIdx.x * ROWSPB + w * 16 + kb * 4 + j;
            int b2 = rr >> 14, pos2 = (rr >> 2) & (L - 1), ns2 = rr & 3;
            int n = bidx[j];
            out[(size_t)BB * C2 * L + ((size_t)b2 * NG + ns2) * L + pos2] = (float)n;
            const float4* pn = (const float4*)(prior + (size_t)n * 8);
            float4 uu = pn[0], vv = pn[1];
            float sv[8] = {uu.x, uu.y, uu.z, uu.w, vv.x, vv.y, vv.z, vv.w};
            #pragma unroll
            for (int g = 0; g < 8; ++g) {
                out[((size_t)b2 * C2 + g * NG + ns2) * L + pos2] = sv[g];
            }
        }
    }
}

extern "C" void kernel_launch(void* const* d_in, const int* in_sizes, int n_in,
                              void* d_out, int out_size, void* d_ws, size_t ws_size,
                              hipStream_t stream) {
    const float* z = (const float*)d_in[0];
    const float* prior = (const float*)d_in[1];
    float* out = (float*)d_out;
    dim3 grid((BB * L * NG) / ROWSPB);   // 65536 rows / 128 = 512 blocks
    dim3 block(TPB);
    hipLaunchKernelGGL(gqreg_kernel, grid, block, 0, stream, z, prior, out);
}